// Round 1
// 236.947 us; speedup vs baseline: 1.0481x; 1.0481x over previous
//
#include <hip/hip_runtime.h>
#include <hip/hip_bf16.h>

using bf16 = __hip_bfloat16;

#define D_DIM 512
#define C_DIM 2048
#define U_DIM 4
#define DK 64

typedef __attribute__((ext_vector_type(8))) short short8;
typedef __attribute__((ext_vector_type(4))) float f32x4;

__device__ __forceinline__ float dload(const void* p, size_t i, int f) {
    return f ? ((const float*)p)[i] : __bfloat162float(((const bf16*)p)[i]);
}
__device__ __forceinline__ unsigned f2bf(float x) {
    bf16 b = __float2bfloat16(x);
    return (unsigned)*(unsigned short*)&b;
}

// ---------------------------------------------------------------------------
__global__ void detect_kernel(const void* __restrict__ x, int* __restrict__ flag) {
    const bf16* xb = (const bf16*)x;
    int tid = threadIdx.x;
    int cnt = 0;
    for (int i = tid; i < 8192; i += 256) {
        float a = fabsf(__bfloat162float(xb[i]));
        if (!(a <= 100.0f)) cnt++;
    }
    #pragma unroll
    for (int o = 32; o > 0; o >>= 1) cnt += __shfl_down(cnt, o);
    __shared__ int sred[4];
    if ((tid & 63) == 0) sred[tid >> 6] = cnt;
    __syncthreads();
    if (tid == 0) {
        int c = sred[0] + sred[1] + sred[2] + sred[3];
        *flag = (c > 400) ? 1 : 0;
    }
}

// ---------------------------------------------------------------------------
// A-fragment pack body: LN stats in-register (16 lanes per row, shfl reduce).
// ---------------------------------------------------------------------------
template <bool LN>
__device__ __forceinline__ void pack_a_body(const void* __restrict__ X, int xf, int f,
                                            const void* __restrict__ lnw,
                                            const void* __restrict__ lnb,
                                            uint4* __restrict__ Af, int tt) {
    int m = threadIdx.x >> 4;
    int kbL = threadIdx.x & 15;
    int row = tt * 16 + m;
    float v[32];
    float s = 0.0f, ss = 0.0f;
    #pragma unroll
    for (int i = 0; i < 4; ++i) {
        int k0 = (kbL + i * 16) * 8;
        #pragma unroll
        for (int j = 0; j < 8; ++j) {
            float x = dload(X, (size_t)row * D_DIM + k0 + j, xf);
            v[i * 8 + j] = x;
            s += x; ss += x * x;
        }
    }
    float mu = 0.0f, rs = 1.0f;
    if (LN) {
        #pragma unroll
        for (int o = 1; o < 16; o <<= 1) { s += __shfl_xor(s, o); ss += __shfl_xor(ss, o); }
        mu = s * (1.0f / D_DIM);
        float var = ss * (1.0f / D_DIM) - mu * mu;
        rs = rsqrtf(var + 1e-5f);
    }
    #pragma unroll
    for (int i = 0; i < 4; ++i) {
        int kb = kbL + i * 16;
        unsigned pk[4];
        #pragma unroll
        for (int jp = 0; jp < 4; ++jp) {
            int k0 = kb * 8 + jp * 2;
            float v0 = v[i * 8 + jp * 2];
            float v1 = v[i * 8 + jp * 2 + 1];
            if (LN) {
                v0 = (v0 - mu) * rs * dload(lnw, k0, f) + dload(lnb, k0, f);
                v1 = (v1 - mu) * rs * dload(lnw, k0 + 1, f) + dload(lnb, k0 + 1, f);
            }
            pk[jp] = f2bf(v0) | (f2bf(v1) << 16);
        }
        uint4 wv = {pk[0], pk[1], pk[2], pk[3]};
        Af[((size_t)tt * 64 + kb) * 16 + m] = wv;
    }
}

template <bool LN>
__global__ __launch_bounds__(256, 1)
void pack_a_kernel(const void* __restrict__ X, int x_raw,
                   const void* __restrict__ lnw, const void* __restrict__ lnb,
                   uint4* __restrict__ Af, const int* __restrict__ flagp) {
    int f = *flagp;
    pack_a_body<LN>(X, x_raw ? f : 1, f, lnw, lnb, Af, blockIdx.x);
}

// ---------------------------------------------------------------------------
// Weight pack body (one 64x64 tile of one weight into bf16 B-fragments).
// ---------------------------------------------------------------------------
__device__ __forceinline__ void pack_w_body(const void* __restrict__ W,
                                            uint4* __restrict__ Bf, int f, int b,
                                            float (*t)[65]) {
    int n0 = (b & 7) * 64, k0 = (b >> 3) * 64;
    int tid = threadIdx.x;
    for (int i = 0; i < 16; ++i) {
        int e = i * 256 + tid;
        int r = e >> 6, c = e & 63;
        t[r][c] = dload(W, (size_t)(k0 + r) * D_DIM + n0 + c, f);
    }
    __syncthreads();
    #pragma unroll
    for (int i = 0; i < 2; ++i) {
        int e = i * 256 + tid;
        int nl = e & 63, kbl = e >> 6;
        unsigned pk[4];
        #pragma unroll
        for (int jp = 0; jp < 4; ++jp)
            pk[jp] = f2bf(t[kbl * 8 + jp * 2][nl]) | (f2bf(t[kbl * 8 + jp * 2 + 1][nl]) << 16);
        uint4 wv = {pk[0], pk[1], pk[2], pk[3]};
        int n = n0 + nl;
        Bf[(((size_t)(n >> 4)) * 64 + (k0 / 8 + kbl)) * 16 + (n & 15)] = wv;
    }
}

// ---------------------------------------------------------------------------
// FUSED pack: blocks [0,64) me->Aq, [64,576) ck->Ak, [576,704) cv->Av,
// [704,1024) the 5 weight tensors (64 tiles each) -> B-fragments.
// All branches depend only on flagp, so one launch replaces two and the
// under-occupied weight pack hides under the 704-block A-pack.
// ---------------------------------------------------------------------------
__global__ __launch_bounds__(256, 1)
void pack_all_kernel(const void* __restrict__ me, const void* __restrict__ l1w, const void* __restrict__ l1b,
                     const void* __restrict__ ck, const void* __restrict__ l2w, const void* __restrict__ l2b,
                     const void* __restrict__ cv, const void* __restrict__ l3w, const void* __restrict__ l3b,
                     uint4* __restrict__ Aq, uint4* __restrict__ Ak, uint4* __restrict__ Av,
                     const void* W0, const void* W1, const void* W2,
                     const void* W3, const void* W4,
                     uint4* B0, uint4* B1, uint4* B2, uint4* B3, uint4* B4,
                     const int* __restrict__ flagp) {
    __shared__ float t[64][65];
    int f = *flagp;
    int b = blockIdx.x;
    if (b < 64)       pack_a_body<true>(me, f, f, l1w, l1b, Aq, b);
    else if (b < 576) pack_a_body<true>(ck, f, f, l2w, l2b, Ak, b - 64);
    else if (b < 704) pack_a_body<true>(cv, f, f, l3w, l3b, Av, b - 576);
    else {
        const void* Ws[5] = {W0, W1, W2, W3, W4};
        uint4* Bs[5] = {B0, B1, B2, B3, B4};
        int c = b - 704;
        pack_w_body(Ws[c >> 6], Bs[c >> 6], f, c & 63, t);
    }
}

// ---------------------------------------------------------------------------
// Fragment MFMA GEMM body, templated epilogue:
// OUT=0 fp32 Y; OUT=1 score-frag (q); OUT=2 PV B-frag (v);
// OUT=3 u-split score-B frag (k): nt = ctx_tile*4 + u.
// ---------------------------------------------------------------------------
template <int OUT>
__device__ __forceinline__ void mfma_gemm_body(const uint4* __restrict__ Af,
                                               const uint4* __restrict__ Bf,
                                               const void* __restrict__ bias,
                                               float* __restrict__ Y,
                                               uint4* __restrict__ Fout, int Rtt,
                                               int f, int bx, int by,
                                               float (*t)[65]) {
    int w = threadIdx.x >> 6, lane = threadIdx.x & 63;
    int q = lane >> 4, mn = lane & 15;
    int mt = by * 4 + w;
    int nt0 = bx * 4;
    f32x4 acc[4] = {{0.f,0.f,0.f,0.f},{0.f,0.f,0.f,0.f},{0.f,0.f,0.f,0.f},{0.f,0.f,0.f,0.f}};
    for (int kw = 0; kw < 16; ++kw) {
        short8 a = *(const short8*)(Af + ((size_t)mt * 64 + kw * 4 + q) * 16 + mn);
        #pragma unroll
        for (int i = 0; i < 4; ++i) {
            short8 b = *(const short8*)(Bf + (((size_t)(nt0 + i)) * 64 + kw * 4 + q) * 16 + mn);
            acc[i] = __builtin_amdgcn_mfma_f32_16x16x32_bf16(a, b, acc[i], 0, 0, 0);
        }
    }
    if constexpr (OUT == 0) {
        #pragma unroll
        for (int i = 0; i < 4; ++i) {
            int col = (nt0 + i) * 16 + mn;
            float bv = dload(bias, col, f);
            #pragma unroll
            for (int r = 0; r < 4; ++r)
                Y[(size_t)(mt * 16 + q * 4 + r) * D_DIM + col] = acc[i][r] + bv;
        }
    } else {
        #pragma unroll
        for (int i = 0; i < 4; ++i) {
            float bv = dload(bias, (nt0 + i) * 16 + mn, f);
            #pragma unroll
            for (int r = 0; r < 4; ++r)
                t[w * 16 + q * 4 + r][i * 16 + mn] = acc[i][r] + bv;
        }
        __syncthreads();
        int h = bx;
        if constexpr (OUT == 1) {
            #pragma unroll
            for (int e0 = 0; e0 < 2; ++e0) {
                int e = e0 * 256 + threadIdx.x;
                int m = e & 15, kb = (e >> 4) & 7, ttl = e >> 7;
                const float* src = &t[ttl * 16 + m][kb * 8];
                uint4 wv;
                wv.x = f2bf(src[0]) | (f2bf(src[1]) << 16);
                wv.y = f2bf(src[2]) | (f2bf(src[3]) << 16);
                wv.z = f2bf(src[4]) | (f2bf(src[5]) << 16);
                wv.w = f2bf(src[6]) | (f2bf(src[7]) << 16);
                Fout[(((size_t)h * Rtt + by * 4 + ttl) * 8 + kb) * 16 + m] = wv;
            }
        } else if constexpr (OUT == 2) {
            #pragma unroll
            for (int e0 = 0; e0 < 2; ++e0) {
                int e = e0 * 256 + threadIdx.x;
                int lane2 = e & 63, nt = (e >> 6) & 3, ctl = e >> 8;
                int nm2 = lane2 & 15, q2 = lane2 >> 4;
                int col = nt * 16 + nm2;
                int rb = ctl * 32 + q2 * 8;
                uint4 wv;
                wv.x = f2bf(t[rb + 0][col]) | (f2bf(t[rb + 1][col]) << 16);
                wv.y = f2bf(t[rb + 2][col]) | (f2bf(t[rb + 3][col]) << 16);
                wv.z = f2bf(t[rb + 4][col]) | (f2bf(t[rb + 5][col]) << 16);
                wv.w = f2bf(t[rb + 6][col]) | (f2bf(t[rb + 7][col]) << 16);
                Fout[(((size_t)h * 64 + by * 2 + ctl) * 4 + nt) * 64 + lane2] = wv;
            }
        } else {
            #pragma unroll
            for (int e0 = 0; e0 < 2; ++e0) {
                int e = e0 * 256 + threadIdx.x;
                int m2 = e & 15, kb = (e >> 4) & 7, u = e >> 7;
                const float* src = &t[m2 * 4 + u][kb * 8];
                uint4 wv;
                wv.x = f2bf(src[0]) | (f2bf(src[1]) << 16);
                wv.y = f2bf(src[2]) | (f2bf(src[3]) << 16);
                wv.z = f2bf(src[4]) | (f2bf(src[5]) << 16);
                wv.w = f2bf(src[6]) | (f2bf(src[7]) << 16);
                int nt = by * 4 + u;
                Fout[(((size_t)h * 512 + nt) * 8 + kb) * 16 + m2] = wv;
            }
        }
    }
}

template <int OUT>
__global__ __launch_bounds__(256, 1)
void mfma_gemm_kernel(const uint4* __restrict__ Af, const uint4* __restrict__ Bf,
                      const void* __restrict__ bias, float* __restrict__ Y,
                      uint4* __restrict__ Fout, int Rtt,
                      const int* __restrict__ flagp) {
    __shared__ float t[64][65];
    mfma_gemm_body<OUT>(Af, Bf, bias, Y, Fout, Rtt, *flagp, blockIdx.x, blockIdx.y, t);
}

// ---------------------------------------------------------------------------
// FUSED q/k/v projection GEMMs — one launch, blocks:
// [0,1024): K (OUT=3, grid was 8x128), [1024,1280): V (OUT=2, 8x32),
// [1280,1408): Q (OUT=1, 8x16). All depend only on the pack outputs, so
// fusing removes two launches and fills the machine during the small GEMMs.
// ---------------------------------------------------------------------------
__global__ __launch_bounds__(256, 1)
void gemm_qkv_kernel(const uint4* __restrict__ Aq, const uint4* __restrict__ Ak,
                     const uint4* __restrict__ Av,
                     const uint4* __restrict__ wfq, const uint4* __restrict__ wfk,
                     const uint4* __restrict__ wfv,
                     const void* __restrict__ bq, const void* __restrict__ bk,
                     const void* __restrict__ bv,
                     uint4* __restrict__ qf, uint4* __restrict__ kf,
                     uint4* __restrict__ vf,
                     const int* __restrict__ flagp) {
    __shared__ float t[64][65];
    int f = *flagp;
    int b = blockIdx.x;
    if (b < 1024) {
        mfma_gemm_body<3>(Ak, wfk, bk, nullptr, kf, 512, f, b & 7, b >> 3, t);
    } else if (b < 1280) {
        int c = b - 1024;
        mfma_gemm_body<2>(Av, wfv, bv, nullptr, vf, 0, f, c & 7, c >> 3, t);
    } else {
        int c = b - 1280;
        mfma_gemm_body<1>(Aq, wfq, bq, nullptr, qf, 64, f, c & 7, c >> 3, t);
    }
}

// ---------------------------------------------------------------------------
// FUSED MFMA flash attention — TWO-PASS register-resident softmax.
// This round: s_setprio(1) around the MFMA clusters (T5; measured +4-7% on
// independent-wave attention blocks, which is exactly this structure).
// ---------------------------------------------------------------------------
__global__ __launch_bounds__(256, 1)
void attn_fused_kernel(const uint4* __restrict__ qf, const uint4* __restrict__ kf,
                       const uint4* __restrict__ vf,
                       float* __restrict__ pacc, float* __restrict__ pm,
                       float* __restrict__ pl) {
    __shared__ float sp[4][16][36];
    int tid = threadIdx.x;
    int w = tid >> 6, lane = tid & 63;
    int q = lane >> 4, nm = lane & 15;
    int b = blockIdx.x;
    int s = b & 7;
    int h = (b >> 3) & 7;
    int qb = b >> 6;
    int mt = qb * 4 + w;

    short8 a0 = *(const short8*)(qf + (((size_t)h * 64 + mt) * 8 + q) * 16 + nm);
    short8 a1 = *(const short8*)(qf + (((size_t)h * 64 + mt) * 8 + 4 + q) * 16 + nm);

    // Phase 1: scores for all 8 super-tiles (16 ctx16-tiles), MaxSim over u.
    f32x4 sc[8][2];
    #pragma unroll
    for (int st = 0; st < 8; ++st) {
        #pragma unroll
        for (int hh = 0; hh < 2; ++hh) {
            int ct16 = (s * 8 + st) * 2 + hh;
            f32x4 scv = {-1e30f, -1e30f, -1e30f, -1e30f};
            __builtin_amdgcn_s_setprio(1);
            #pragma unroll
            for (int u = 0; u < 4; ++u) {
                int nt = ct16 * 4 + u;
                short8 b0 = *(const short8*)(kf + (((size_t)h * 512 + nt) * 8 + q) * 16 + nm);
                short8 b1 = *(const short8*)(kf + (((size_t)h * 512 + nt) * 8 + 4 + q) * 16 + nm);
                f32x4 acc = {0.0f, 0.0f, 0.0f, 0.0f};
                acc = __builtin_amdgcn_mfma_f32_16x16x32_bf16(a0, b0, acc, 0, 0, 0);
                acc = __builtin_amdgcn_mfma_f32_16x16x32_bf16(a1, b1, acc, 0, 0, 0);
                #pragma unroll
                for (int r = 0; r < 4; ++r) scv[r] = fmaxf(scv[r], acc[r]);
            }
            __builtin_amdgcn_s_setprio(0);
            #pragma unroll
            for (int r = 0; r < 4; ++r) sc[st][hh][r] = scv[r] * 0.125f;  // 1/sqrt(dk)
        }
    }

    // Phase 2: split max per query row (one shuffle tree, no online alpha).
    float mrow[4], lrow[4];
    #pragma unroll
    for (int r = 0; r < 4; ++r) {
        float m = sc[0][0][r];
        #pragma unroll
        for (int st = 0; st < 8; ++st) {
            m = fmaxf(m, sc[st][0][r]);
            m = fmaxf(m, sc[st][1][r]);
        }
        m = fmaxf(m, __shfl_xor(m, 1));
        m = fmaxf(m, __shfl_xor(m, 2));
        m = fmaxf(m, __shfl_xor(m, 4));
        m = fmaxf(m, __shfl_xor(m, 8));
        mrow[r] = m;
        lrow[r] = 0.0f;
    }

    // Phase 3: exp -> P-frag via per-wave LDS -> PV MFMAs (K=32 per tile).
    f32x4 acc_o[4] = {{0.f,0.f,0.f,0.f},{0.f,0.f,0.f,0.f},{0.f,0.f,0.f,0.f},{0.f,0.f,0.f,0.f}};
    #pragma unroll
    for (int st = 0; st < 8; ++st) {
        #pragma unroll
        for (int r = 0; r < 4; ++r) {
            float p0 = __expf(sc[st][0][r] - mrow[r]);
            float p1 = __expf(sc[st][1][r] - mrow[r]);
            sp[w][q * 4 + r][nm] = p0;
            sp[w][q * 4 + r][16 + nm] = p1;
            lrow[r] += p0 + p1;
        }
        float4 pa0 = *(const float4*)&sp[w][nm][q * 8];
        float4 pa1 = *(const float4*)&sp[w][nm][q * 8 + 4];
        uint4 av;
        av.x = f2bf(pa0.x) | (f2bf(pa0.y) << 16);
        av.y = f2bf(pa0.z) | (f2bf(pa0.w) << 16);
        av.z = f2bf(pa1.x) | (f2bf(pa1.y) << 16);
        av.w = f2bf(pa1.z) | (f2bf(pa1.w) << 16);
        short8 ap = *(short8*)&av;
        int ct32 = s * 8 + st;
        __builtin_amdgcn_s_setprio(1);
        #pragma unroll
        for (int nt2 = 0; nt2 < 4; ++nt2) {
            short8 bv = *(const short8*)(vf + (((size_t)h * 64 + ct32) * 4 + nt2) * 64 + lane);
            acc_o[nt2] = __builtin_amdgcn_mfma_f32_16x16x32_bf16(ap, bv, acc_o[nt2], 0, 0, 0);
        }
        __builtin_amdgcn_s_setprio(0);
    }

    // Row-sum reduction across the 16 context lanes (once).
    #pragma unroll
    for (int r = 0; r < 4; ++r) {
        float ps = lrow[r];
        ps += __shfl_xor(ps, 1);
        ps += __shfl_xor(ps, 2);
        ps += __shfl_xor(ps, 4);
        ps += __shfl_xor(ps, 8);
        lrow[r] = ps;
    }

    int p_idx = ((qb * 8 + h) << 3) + s;
    float* po = pacc + ((size_t)p_idx * 64 + w * 16) * 64;
    #pragma unroll
    for (int nt2 = 0; nt2 < 4; ++nt2)
        #pragma unroll
        for (int r = 0; r < 4; ++r)
            po[(q * 4 + r) * 64 + nt2 * 16 + nm] = acc_o[nt2][r];
    if (nm == 0) {
        #pragma unroll
        for (int r = 0; r < 4; ++r) {
            pm[p_idx * 64 + w * 16 + q * 4 + r] = mrow[r];
            pl[p_idx * 64 + w * 16 + q * 4 + r] = lrow[r];
        }
    }
}

// Merge 8 c-split partials; emit wo-GEMM A-fragments directly.
__global__ void attn_merge2_kernel(const float* __restrict__ pacc, const float* __restrict__ pm,
                                   const float* __restrict__ pl, uint4* __restrict__ oAf) {
    int b = blockIdx.x;                // qb*8 + h
    int qb = b >> 3, h = b & 7;
    int tid = threadIdx.x;
    int t_loc = tid & 63, dg = tid >> 6;
    int p0 = b * 8;
    float M = -1e30f;
    #pragma unroll
    for (int s = 0; s < 8; ++s) M = fmaxf(M, pm[(p0 + s) * 64 + t_loc]);
    float L = 0.0f;
    float4 o[4] = {};
    #pragma unroll
    for (int s = 0; s < 8; ++s) {
        float e = __expf(pm[(p0 + s) * 64 + t_loc] - M);
        L += pl[(p0 + s) * 64 + t_loc] * e;
        const float4* po = (const float4*)(pacc + ((size_t)(p0 + s) * 64 + t_loc) * 64 + dg * 16);
        #pragma unroll
        for (int d = 0; d < 4; ++d) {
            float4 v = po[d];
            o[d].x += v.x * e; o[d].y += v.y * e; o[d].z += v.z * e; o[d].w += v.w * e;
        }
    }
    float inv = 1.0f / L;
    int t = qb * 64 + t_loc;
    int tt = t >> 4, m = t & 15;
    int kb0 = h * 8 + dg * 2;
    uint4 u0, u1;
    u0.x = f2bf(o[0].x * inv) | (f2bf(o[0].y * inv) << 16);
    u0.y = f2bf(o[0].z * inv) | (f2bf(o[0].w * inv) << 16);
    u0.z = f2bf(o[1].x * inv) | (f2bf(o[1].y * inv) << 16);
    u0.w = f2bf(o[1].z * inv) | (f2bf(o[1].w * inv) << 16);
    u1.x = f2bf(o[2].x * inv) | (f2bf(o[2].y * inv) << 16);
    u1.y = f2bf(o[2].z * inv) | (f2bf(o[2].w * inv) << 16);
    u1.z = f2bf(o[3].x * inv) | (f2bf(o[3].y * inv) << 16);
    u1.w = f2bf(o[3].z * inv) | (f2bf(o[3].w * inv) << 16);
    oAf[((size_t)tt * 64 + kb0) * 16 + m] = u0;
    oAf[((size_t)tt * 64 + kb0 + 1) * 16 + m] = u1;
}

extern "C" void kernel_launch(void* const* d_in, const int* in_sizes, int n_in,
                              void* d_out, int out_size, void* d_ws, size_t ws_size,
                              hipStream_t stream) {
    const void* model_embed = d_in[0];
    const void* ctx_key     = d_in[1];
    const void* ctx_val     = d_in[2];
    const void* ln1w = d_in[3];  const void* ln1b = d_in[4];
    const void* ln2w = d_in[5];  const void* ln2b = d_in[6];
    const void* ln3w = d_in[7];  const void* ln3b = d_in[8];
    const void* ln4w = d_in[9];  const void* ln4b = d_in[10];
    const void* wq = d_in[11];   const void* bq = d_in[12];
    const void* wk = d_in[13];   const void* bk = d_in[14];
    const void* wv = d_in[15];   const void* bv = d_in[16];
    const void* wo = d_in[17];   const void* bo = d_in[18];
    const void* wp = d_in[19];   const void* bp = d_in[20];

    int*   flagp = (int*)d_ws;
    float* ws    = (float*)d_ws + 16;
    float* o1    = ws;                         // 524288 fp32
    float* qTf   = o1 + 524288;                // qf   262144 fl (1 MB)
    float* kTf   = qTf + 262144;               // kf  2097152 fl (8 MB)
    float* Aqf   = kTf + 2097152;              // Aq   262144 fl
    float* Akf   = Aqf + 262144;               // Ak  2097152 fl
    float* Avf   = Akf + 2097152;              // Av   524288 fl
    float* vff   = Avf + 524288;               // vf   524288 fl (also oAf)
    float* pacc2 = vff + 524288;               // 4194304 fl (16 MB)
    float* pm2   = pacc2 + 4194304;            // 65536
    float* pl2   = pm2 + 65536;                // 65536
    float* wfr   = pl2 + 65536;                // 655360 fl (5 W-frags)

    uint4* qf  = (uint4*)qTf;
    uint4* kf  = (uint4*)kTf;
    uint4* Aq  = (uint4*)Aqf;
    uint4* Ak  = (uint4*)Akf;
    uint4* Av  = (uint4*)Avf;
    uint4* vf  = (uint4*)vff;
    uint4* oAf = (uint4*)vff;                  // reuse after attn consumes vf
    uint4* wfq = (uint4*)wfr;
    uint4* wfk = wfq + 32768;
    uint4* wfv = wfk + 32768;
    uint4* wfo = wfv + 32768;
    uint4* wfp = wfo + 32768;

    detect_kernel<<<1, 256, 0, stream>>>(model_embed, flagp);

    pack_all_kernel<<<1024, 256, 0, stream>>>(model_embed, ln1w, ln1b,
                                              ctx_key, ln2w, ln2b,
                                              ctx_val, ln3w, ln3b,
                                              Aq, Ak, Av,
                                              wq, wk, wv, wo, wp,
                                              wfq, wfk, wfv, wfo, wfp, flagp);

    gemm_qkv_kernel<<<1408, 256, 0, stream>>>(Aq, Ak, Av, wfq, wfk, wfv,
                                              bq, bk, bv, qf, kf, vf, flagp);

    attn_fused_kernel<<<1024, 256, 0, stream>>>(qf, kf, vf, pacc2, pm2, pl2);
    attn_merge2_kernel<<<128, 256, 0, stream>>>(pacc2, pm2, pl2, oAf);

    mfma_gemm_kernel<0><<<dim3(8, 16), 256, 0, stream>>>(oAf, wfo, bo, o1, nullptr, 0, flagp);
    pack_a_kernel<true><<<64, 256, 0, stream>>>(o1, 0, ln4w, ln4b, Aq, flagp);
    mfma_gemm_kernel<0><<<dim3(8, 16), 256, 0, stream>>>(Aq, wfp, bp, (float*)d_out, nullptr, 0, flagp);

    (void)ws_size;
}

// Round 2
// 195.586 us; speedup vs baseline: 1.2698x; 1.2115x over previous
//
#include <hip/hip_runtime.h>
#include <hip/hip_bf16.h>

using bf16 = __hip_bfloat16;

#define D_DIM 512
#define C_DIM 2048
#define U_DIM 4
#define DK 64

typedef __attribute__((ext_vector_type(8))) short short8;
typedef __attribute__((ext_vector_type(8))) unsigned short ushort8;
typedef __attribute__((ext_vector_type(4))) float f32x4;

__device__ __forceinline__ float dload(const void* p, size_t i, int f) {
    return f ? ((const float*)p)[i] : __bfloat162float(((const bf16*)p)[i]);
}
__device__ __forceinline__ unsigned f2bf(float x) {
    bf16 b = __float2bfloat16(x);
    return (unsigned)*(unsigned short*)&b;
}
__device__ __forceinline__ float bf2f(unsigned short us) {
    unsigned u = ((unsigned)us) << 16;
    return __builtin_bit_cast(float, u);
}

// ---------------------------------------------------------------------------
// Per-block dtype detect (replaces the serial 1-block detect_kernel launch).
// Reads the first 8192 bf16-view elements of model_embed (16 KB, L2-hot after
// the first block) with vector loads; identical predicate/threshold as before.
// ---------------------------------------------------------------------------
__device__ __forceinline__ int block_detect(const void* __restrict__ x) {
    __shared__ int sred[4];
    const bf16* xb = (const bf16*)x;
    int tid = threadIdx.x;
    int cnt = 0;
    #pragma unroll
    for (int i = 0; i < 4; ++i) {
        ushort8 a = *(const ushort8*)(xb + (size_t)(i * 256 + tid) * 8);
        #pragma unroll
        for (int j = 0; j < 8; ++j) {
            float v = fabsf(bf2f(a[j]));
            if (!(v <= 100.0f)) cnt++;
        }
    }
    #pragma unroll
    for (int o = 32; o > 0; o >>= 1) cnt += __shfl_down(cnt, o);
    if ((tid & 63) == 0) sred[tid >> 6] = cnt;
    __syncthreads();
    int c = sred[0] + sred[1] + sred[2] + sred[3];
    return (c > 400) ? 1 : 0;
}

// ---------------------------------------------------------------------------
// A-fragment pack body: dtype now a COMPILE-TIME template param (XF for the
// activation, WF for ln weights) so all loads vectorize (float4 / ushort8).
// LN stats in-register (16 lanes per row, shfl reduce). Math order identical
// to the previous scalar version.
// ---------------------------------------------------------------------------
template <bool LN, bool XF, bool WF>
__device__ __forceinline__ void pack_a_body(const void* __restrict__ X,
                                            const void* __restrict__ lnw,
                                            const void* __restrict__ lnb,
                                            uint4* __restrict__ Af, int tt) {
    int m = threadIdx.x >> 4;
    int kbL = threadIdx.x & 15;
    int row = tt * 16 + m;
    float v[32];
    float s = 0.0f, ss = 0.0f;
    #pragma unroll
    for (int i = 0; i < 4; ++i) {
        int k0 = (kbL + i * 16) * 8;
        if constexpr (XF) {
            const float4* p = (const float4*)((const float*)X + (size_t)row * D_DIM + k0);
            float4 a = p[0], b = p[1];
            v[i*8+0] = a.x; v[i*8+1] = a.y; v[i*8+2] = a.z; v[i*8+3] = a.w;
            v[i*8+4] = b.x; v[i*8+5] = b.y; v[i*8+6] = b.z; v[i*8+7] = b.w;
        } else {
            ushort8 a = *(const ushort8*)((const bf16*)X + (size_t)row * D_DIM + k0);
            #pragma unroll
            for (int j = 0; j < 8; ++j) v[i*8+j] = bf2f(a[j]);
        }
        #pragma unroll
        for (int j = 0; j < 8; ++j) { float x = v[i*8+j]; s += x; ss += x * x; }
    }
    float mu = 0.0f, rs = 1.0f;
    if (LN) {
        #pragma unroll
        for (int o = 1; o < 16; o <<= 1) { s += __shfl_xor(s, o); ss += __shfl_xor(ss, o); }
        mu = s * (1.0f / D_DIM);
        float var = ss * (1.0f / D_DIM) - mu * mu;
        rs = rsqrtf(var + 1e-5f);
    }
    #pragma unroll
    for (int i = 0; i < 4; ++i) {
        int kb = kbL + i * 16;
        int k0 = kb * 8;
        float lw[8], lb[8];
        if (LN) {
            if constexpr (WF) {
                const float4* pw = (const float4*)((const float*)lnw + k0);
                const float4* pb = (const float4*)((const float*)lnb + k0);
                float4 w0 = pw[0], w1 = pw[1], b0 = pb[0], b1 = pb[1];
                lw[0]=w0.x; lw[1]=w0.y; lw[2]=w0.z; lw[3]=w0.w;
                lw[4]=w1.x; lw[5]=w1.y; lw[6]=w1.z; lw[7]=w1.w;
                lb[0]=b0.x; lb[1]=b0.y; lb[2]=b0.z; lb[3]=b0.w;
                lb[4]=b1.x; lb[5]=b1.y; lb[6]=b1.z; lb[7]=b1.w;
            } else {
                ushort8 w8 = *(const ushort8*)((const bf16*)lnw + k0);
                ushort8 b8 = *(const ushort8*)((const bf16*)lnb + k0);
                #pragma unroll
                for (int j = 0; j < 8; ++j) { lw[j] = bf2f(w8[j]); lb[j] = bf2f(b8[j]); }
            }
        }
        unsigned pk[4];
        #pragma unroll
        for (int jp = 0; jp < 4; ++jp) {
            float v0 = v[i * 8 + jp * 2];
            float v1 = v[i * 8 + jp * 2 + 1];
            if (LN) {
                v0 = (v0 - mu) * rs * lw[jp * 2] + lb[jp * 2];
                v1 = (v1 - mu) * rs * lw[jp * 2 + 1] + lb[jp * 2 + 1];
            }
            pk[jp] = f2bf(v0) | (f2bf(v1) << 16);
        }
        uint4 wv = {pk[0], pk[1], pk[2], pk[3]};
        Af[((size_t)tt * 64 + kb) * 16 + m] = wv;
    }
}

// o1 re-pack (X always fp32; ln4 dtype follows flag).
template <bool LN>
__global__ __launch_bounds__(256, 1)
void pack_a_kernel(const void* __restrict__ X, int x_raw,
                   const void* __restrict__ lnw, const void* __restrict__ lnb,
                   uint4* __restrict__ Af, const int* __restrict__ flagp) {
    int f = *flagp;
    (void)x_raw;
    if (f) pack_a_body<LN, true, true>(X, lnw, lnb, Af, blockIdx.x);
    else   pack_a_body<LN, true, false>(X, lnw, lnb, Af, blockIdx.x);
}

// ---------------------------------------------------------------------------
// Weight pack body (one 64x64 tile into bf16 B-fragments), dtype templated.
// ---------------------------------------------------------------------------
template <bool WF>
__device__ __forceinline__ void pack_w_body(const void* __restrict__ W,
                                            uint4* __restrict__ Bf, int b,
                                            float (*t)[65]) {
    int n0 = (b & 7) * 64, k0 = (b >> 3) * 64;
    int tid = threadIdx.x;
    if constexpr (WF) {
        #pragma unroll
        for (int i = 0; i < 4; ++i) {
            int e = i * 256 + tid;            // vec4 index in [0,1024)
            int r = e >> 4, c = (e & 15) * 4;
            float4 a = *(const float4*)((const float*)W + (size_t)(k0 + r) * D_DIM + n0 + c);
            t[r][c] = a.x; t[r][c+1] = a.y; t[r][c+2] = a.z; t[r][c+3] = a.w;
        }
    } else {
        #pragma unroll
        for (int i = 0; i < 2; ++i) {
            int e = i * 256 + tid;            // vec8 index in [0,512)
            int r = e >> 3, c = (e & 7) * 8;
            ushort8 a = *(const ushort8*)((const bf16*)W + (size_t)(k0 + r) * D_DIM + n0 + c);
            #pragma unroll
            for (int j = 0; j < 8; ++j) t[r][c + j] = bf2f(a[j]);
        }
    }
    __syncthreads();
    #pragma unroll
    for (int i = 0; i < 2; ++i) {
        int e = i * 256 + tid;
        int nl = e & 63, kbl = e >> 6;
        unsigned pk[4];
        #pragma unroll
        for (int jp = 0; jp < 4; ++jp)
            pk[jp] = f2bf(t[kbl * 8 + jp * 2][nl]) | (f2bf(t[kbl * 8 + jp * 2 + 1][nl]) << 16);
        uint4 wv = {pk[0], pk[1], pk[2], pk[3]};
        int n = n0 + nl;
        Bf[(((size_t)(n >> 4)) * 64 + (k0 / 8 + kbl)) * 16 + (n & 15)] = wv;
    }
}

// ---------------------------------------------------------------------------
// FUSED pack: blocks [0,64) me->Aq, [64,576) ck->Ak, [576,704) cv->Av,
// [704,1024) the 5 weight tensors (64 tiles each) -> B-fragments.
// Each block detects the dtype itself (no serial detect launch); block 0
// publishes the flag for downstream bias loads.
// ---------------------------------------------------------------------------
__global__ __launch_bounds__(256, 1)
void pack_all_kernel(const void* __restrict__ me, const void* __restrict__ l1w, const void* __restrict__ l1b,
                     const void* __restrict__ ck, const void* __restrict__ l2w, const void* __restrict__ l2b,
                     const void* __restrict__ cv, const void* __restrict__ l3w, const void* __restrict__ l3b,
                     uint4* __restrict__ Aq, uint4* __restrict__ Ak, uint4* __restrict__ Av,
                     const void* W0, const void* W1, const void* W2,
                     const void* W3, const void* W4,
                     uint4* B0, uint4* B1, uint4* B2, uint4* B3, uint4* B4,
                     int* __restrict__ flagp) {
    __shared__ float t[64][65];
    int f = block_detect(me);
    if (blockIdx.x == 0 && threadIdx.x == 0) *flagp = f;
    int b = blockIdx.x;
    const void* Ws[5] = {W0, W1, W2, W3, W4};
    uint4* Bs[5] = {B0, B1, B2, B3, B4};
    if (f) {
        if (b < 64)       pack_a_body<true, true, true>(me, l1w, l1b, Aq, b);
        else if (b < 576) pack_a_body<true, true, true>(ck, l2w, l2b, Ak, b - 64);
        else if (b < 704) pack_a_body<true, true, true>(cv, l3w, l3b, Av, b - 576);
        else { int c = b - 704; pack_w_body<true>(Ws[c >> 6], Bs[c >> 6], c & 63, t); }
    } else {
        if (b < 64)       pack_a_body<true, false, false>(me, l1w, l1b, Aq, b);
        else if (b < 576) pack_a_body<true, false, false>(ck, l2w, l2b, Ak, b - 64);
        else if (b < 704) pack_a_body<true, false, false>(cv, l3w, l3b, Av, b - 576);
        else { int c = b - 704; pack_w_body<false>(Ws[c >> 6], Bs[c >> 6], c & 63, t); }
    }
}

// ---------------------------------------------------------------------------
// Fragment MFMA GEMM body, templated epilogue:
// OUT=0 fp32 Y; OUT=1 score-frag (q); OUT=2 PV B-frag (v);
// OUT=3 u-split score-B frag (k): nt = ctx_tile*4 + u.
// ---------------------------------------------------------------------------
template <int OUT>
__device__ __forceinline__ void mfma_gemm_body(const uint4* __restrict__ Af,
                                               const uint4* __restrict__ Bf,
                                               const void* __restrict__ bias,
                                               float* __restrict__ Y,
                                               uint4* __restrict__ Fout, int Rtt,
                                               int f, int bx, int by,
                                               float (*t)[65]) {
    int w = threadIdx.x >> 6, lane = threadIdx.x & 63;
    int q = lane >> 4, mn = lane & 15;
    int mt = by * 4 + w;
    int nt0 = bx * 4;
    f32x4 acc[4] = {{0.f,0.f,0.f,0.f},{0.f,0.f,0.f,0.f},{0.f,0.f,0.f,0.f},{0.f,0.f,0.f,0.f}};
    for (int kw = 0; kw < 16; ++kw) {
        short8 a = *(const short8*)(Af + ((size_t)mt * 64 + kw * 4 + q) * 16 + mn);
        #pragma unroll
        for (int i = 0; i < 4; ++i) {
            short8 b = *(const short8*)(Bf + (((size_t)(nt0 + i)) * 64 + kw * 4 + q) * 16 + mn);
            acc[i] = __builtin_amdgcn_mfma_f32_16x16x32_bf16(a, b, acc[i], 0, 0, 0);
        }
    }
    if constexpr (OUT == 0) {
        #pragma unroll
        for (int i = 0; i < 4; ++i) {
            int col = (nt0 + i) * 16 + mn;
            float bv = dload(bias, col, f);
            #pragma unroll
            for (int r = 0; r < 4; ++r)
                Y[(size_t)(mt * 16 + q * 4 + r) * D_DIM + col] = acc[i][r] + bv;
        }
    } else {
        #pragma unroll
        for (int i = 0; i < 4; ++i) {
            float bv = dload(bias, (nt0 + i) * 16 + mn, f);
            #pragma unroll
            for (int r = 0; r < 4; ++r)
                t[w * 16 + q * 4 + r][i * 16 + mn] = acc[i][r] + bv;
        }
        __syncthreads();
        int h = bx;
        if constexpr (OUT == 1) {
            #pragma unroll
            for (int e0 = 0; e0 < 2; ++e0) {
                int e = e0 * 256 + threadIdx.x;
                int m = e & 15, kb = (e >> 4) & 7, ttl = e >> 7;
                const float* src = &t[ttl * 16 + m][kb * 8];
                uint4 wv;
                wv.x = f2bf(src[0]) | (f2bf(src[1]) << 16);
                wv.y = f2bf(src[2]) | (f2bf(src[3]) << 16);
                wv.z = f2bf(src[4]) | (f2bf(src[5]) << 16);
                wv.w = f2bf(src[6]) | (f2bf(src[7]) << 16);
                Fout[(((size_t)h * Rtt + by * 4 + ttl) * 8 + kb) * 16 + m] = wv;
            }
        } else if constexpr (OUT == 2) {
            #pragma unroll
            for (int e0 = 0; e0 < 2; ++e0) {
                int e = e0 * 256 + threadIdx.x;
                int lane2 = e & 63, nt = (e >> 6) & 3, ctl = e >> 8;
                int nm2 = lane2 & 15, q2 = lane2 >> 4;
                int col = nt * 16 + nm2;
                int rb = ctl * 32 + q2 * 8;
                uint4 wv;
                wv.x = f2bf(t[rb + 0][col]) | (f2bf(t[rb + 1][col]) << 16);
                wv.y = f2bf(t[rb + 2][col]) | (f2bf(t[rb + 3][col]) << 16);
                wv.z = f2bf(t[rb + 4][col]) | (f2bf(t[rb + 5][col]) << 16);
                wv.w = f2bf(t[rb + 6][col]) | (f2bf(t[rb + 7][col]) << 16);
                Fout[(((size_t)h * 64 + by * 2 + ctl) * 4 + nt) * 64 + lane2] = wv;
            }
        } else {
            #pragma unroll
            for (int e0 = 0; e0 < 2; ++e0) {
                int e = e0 * 256 + threadIdx.x;
                int m2 = e & 15, kb = (e >> 4) & 7, u = e >> 7;
                const float* src = &t[m2 * 4 + u][kb * 8];
                uint4 wv;
                wv.x = f2bf(src[0]) | (f2bf(src[1]) << 16);
                wv.y = f2bf(src[2]) | (f2bf(src[3]) << 16);
                wv.z = f2bf(src[4]) | (f2bf(src[5]) << 16);
                wv.w = f2bf(src[6]) | (f2bf(src[7]) << 16);
                int nt = by * 4 + u;
                Fout[(((size_t)h * 512 + nt) * 8 + kb) * 16 + m2] = wv;
            }
        }
    }
}

template <int OUT>
__global__ __launch_bounds__(256, 1)
void mfma_gemm_kernel(const uint4* __restrict__ Af, const uint4* __restrict__ Bf,
                      const void* __restrict__ bias, float* __restrict__ Y,
                      uint4* __restrict__ Fout, int Rtt,
                      const int* __restrict__ flagp) {
    __shared__ float t[64][65];
    mfma_gemm_body<OUT>(Af, Bf, bias, Y, Fout, Rtt, *flagp, blockIdx.x, blockIdx.y, t);
}

// ---------------------------------------------------------------------------
// FUSED q/k/v projection GEMMs — one launch, blocks:
// [0,1024): K (OUT=3), [1024,1280): V (OUT=2), [1280,1408): Q (OUT=1).
// ---------------------------------------------------------------------------
__global__ __launch_bounds__(256, 1)
void gemm_qkv_kernel(const uint4* __restrict__ Aq, const uint4* __restrict__ Ak,
                     const uint4* __restrict__ Av,
                     const uint4* __restrict__ wfq, const uint4* __restrict__ wfk,
                     const uint4* __restrict__ wfv,
                     const void* __restrict__ bq, const void* __restrict__ bk,
                     const void* __restrict__ bv,
                     uint4* __restrict__ qf, uint4* __restrict__ kf,
                     uint4* __restrict__ vf,
                     const int* __restrict__ flagp) {
    __shared__ float t[64][65];
    int f = *flagp;
    int b = blockIdx.x;
    if (b < 1024) {
        mfma_gemm_body<3>(Ak, wfk, bk, nullptr, kf, 512, f, b & 7, b >> 3, t);
    } else if (b < 1280) {
        int c = b - 1024;
        mfma_gemm_body<2>(Av, wfv, bv, nullptr, vf, 0, f, c & 7, c >> 3, t);
    } else {
        int c = b - 1280;
        mfma_gemm_body<1>(Aq, wfq, bq, nullptr, qf, 64, f, c & 7, c >> 3, t);
    }
}

// ---------------------------------------------------------------------------
// FUSED MFMA flash attention — TWO-PASS register-resident softmax.
// s_setprio(1) around MFMA clusters (T5; +4-7% on independent-wave attn).
// ---------------------------------------------------------------------------
__global__ __launch_bounds__(256, 1)
void attn_fused_kernel(const uint4* __restrict__ qf, const uint4* __restrict__ kf,
                       const uint4* __restrict__ vf,
                       float* __restrict__ pacc, float* __restrict__ pm,
                       float* __restrict__ pl) {
    __shared__ float sp[4][16][36];
    int tid = threadIdx.x;
    int w = tid >> 6, lane = tid & 63;
    int q = lane >> 4, nm = lane & 15;
    int b = blockIdx.x;
    int s = b & 7;
    int h = (b >> 3) & 7;
    int qb = b >> 6;
    int mt = qb * 4 + w;

    short8 a0 = *(const short8*)(qf + (((size_t)h * 64 + mt) * 8 + q) * 16 + nm);
    short8 a1 = *(const short8*)(qf + (((size_t)h * 64 + mt) * 8 + 4 + q) * 16 + nm);

    // Phase 1: scores for all 8 super-tiles (16 ctx16-tiles), MaxSim over u.
    f32x4 sc[8][2];
    #pragma unroll
    for (int st = 0; st < 8; ++st) {
        #pragma unroll
        for (int hh = 0; hh < 2; ++hh) {
            int ct16 = (s * 8 + st) * 2 + hh;
            f32x4 scv = {-1e30f, -1e30f, -1e30f, -1e30f};
            __builtin_amdgcn_s_setprio(1);
            #pragma unroll
            for (int u = 0; u < 4; ++u) {
                int nt = ct16 * 4 + u;
                short8 b0 = *(const short8*)(kf + (((size_t)h * 512 + nt) * 8 + q) * 16 + nm);
                short8 b1 = *(const short8*)(kf + (((size_t)h * 512 + nt) * 8 + 4 + q) * 16 + nm);
                f32x4 acc = {0.0f, 0.0f, 0.0f, 0.0f};
                acc = __builtin_amdgcn_mfma_f32_16x16x32_bf16(a0, b0, acc, 0, 0, 0);
                acc = __builtin_amdgcn_mfma_f32_16x16x32_bf16(a1, b1, acc, 0, 0, 0);
                #pragma unroll
                for (int r = 0; r < 4; ++r) scv[r] = fmaxf(scv[r], acc[r]);
            }
            __builtin_amdgcn_s_setprio(0);
            #pragma unroll
            for (int r = 0; r < 4; ++r) sc[st][hh][r] = scv[r] * 0.125f;  // 1/sqrt(dk)
        }
    }

    // Phase 2: split max per query row (one shuffle tree, no online alpha).
    float mrow[4], lrow[4];
    #pragma unroll
    for (int r = 0; r < 4; ++r) {
        float m = sc[0][0][r];
        #pragma unroll
        for (int st = 0; st < 8; ++st) {
            m = fmaxf(m, sc[st][0][r]);
            m = fmaxf(m, sc[st][1][r]);
        }
        m = fmaxf(m, __shfl_xor(m, 1));
        m = fmaxf(m, __shfl_xor(m, 2));
        m = fmaxf(m, __shfl_xor(m, 4));
        m = fmaxf(m, __shfl_xor(m, 8));
        mrow[r] = m;
        lrow[r] = 0.0f;
    }

    // Phase 3: exp -> P-frag via per-wave LDS -> PV MFMAs (K=32 per tile).
    f32x4 acc_o[4] = {{0.f,0.f,0.f,0.f},{0.f,0.f,0.f,0.f},{0.f,0.f,0.f,0.f},{0.f,0.f,0.f,0.f}};
    #pragma unroll
    for (int st = 0; st < 8; ++st) {
        #pragma unroll
        for (int r = 0; r < 4; ++r) {
            float p0 = __expf(sc[st][0][r] - mrow[r]);
            float p1 = __expf(sc[st][1][r] - mrow[r]);
            sp[w][q * 4 + r][nm] = p0;
            sp[w][q * 4 + r][16 + nm] = p1;
            lrow[r] += p0 + p1;
        }
        float4 pa0 = *(const float4*)&sp[w][nm][q * 8];
        float4 pa1 = *(const float4*)&sp[w][nm][q * 8 + 4];
        uint4 av;
        av.x = f2bf(pa0.x) | (f2bf(pa0.y) << 16);
        av.y = f2bf(pa0.z) | (f2bf(pa0.w) << 16);
        av.z = f2bf(pa1.x) | (f2bf(pa1.y) << 16);
        av.w = f2bf(pa1.z) | (f2bf(pa1.w) << 16);
        short8 ap = *(short8*)&av;
        int ct32 = s * 8 + st;
        __builtin_amdgcn_s_setprio(1);
        #pragma unroll
        for (int nt2 = 0; nt2 < 4; ++nt2) {
            short8 bv = *(const short8*)(vf + (((size_t)h * 64 + ct32) * 4 + nt2) * 64 + lane);
            acc_o[nt2] = __builtin_amdgcn_mfma_f32_16x16x32_bf16(ap, bv, acc_o[nt2], 0, 0, 0);
        }
        __builtin_amdgcn_s_setprio(0);
    }

    // Row-sum reduction across the 16 context lanes (once).
    #pragma unroll
    for (int r = 0; r < 4; ++r) {
        float ps = lrow[r];
        ps += __shfl_xor(ps, 1);
        ps += __shfl_xor(ps, 2);
        ps += __shfl_xor(ps, 4);
        ps += __shfl_xor(ps, 8);
        lrow[r] = ps;
    }

    int p_idx = ((qb * 8 + h) << 3) + s;
    float* po = pacc + ((size_t)p_idx * 64 + w * 16) * 64;
    #pragma unroll
    for (int nt2 = 0; nt2 < 4; ++nt2)
        #pragma unroll
        for (int r = 0; r < 4; ++r)
            po[(q * 4 + r) * 64 + nt2 * 16 + nm] = acc_o[nt2][r];
    if (nm == 0) {
        #pragma unroll
        for (int r = 0; r < 4; ++r) {
            pm[p_idx * 64 + w * 16 + q * 4 + r] = mrow[r];
            pl[p_idx * 64 + w * 16 + q * 4 + r] = lrow[r];
        }
    }
}

// Merge 8 c-split partials; emit wo-GEMM A-fragments directly.
__global__ void attn_merge2_kernel(const float* __restrict__ pacc, const float* __restrict__ pm,
                                   const float* __restrict__ pl, uint4* __restrict__ oAf) {
    int b = blockIdx.x;                // qb*8 + h
    int qb = b >> 3, h = b & 7;
    int tid = threadIdx.x;
    int t_loc = tid & 63, dg = tid >> 6;
    int p0 = b * 8;
    float M = -1e30f;
    #pragma unroll
    for (int s = 0; s < 8; ++s) M = fmaxf(M, pm[(p0 + s) * 64 + t_loc]);
    float L = 0.0f;
    float4 o[4] = {};
    #pragma unroll
    for (int s = 0; s < 8; ++s) {
        float e = __expf(pm[(p0 + s) * 64 + t_loc] - M);
        L += pl[(p0 + s) * 64 + t_loc] * e;
        const float4* po = (const float4*)(pacc + ((size_t)(p0 + s) * 64 + t_loc) * 64 + dg * 16);
        #pragma unroll
        for (int d = 0; d < 4; ++d) {
            float4 v = po[d];
            o[d].x += v.x * e; o[d].y += v.y * e; o[d].z += v.z * e; o[d].w += v.w * e;
        }
    }
    float inv = 1.0f / L;
    int t = qb * 64 + t_loc;
    int tt = t >> 4, m = t & 15;
    int kb0 = h * 8 + dg * 2;
    uint4 u0, u1;
    u0.x = f2bf(o[0].x * inv) | (f2bf(o[0].y * inv) << 16);
    u0.y = f2bf(o[0].z * inv) | (f2bf(o[0].w * inv) << 16);
    u0.z = f2bf(o[1].x * inv) | (f2bf(o[1].y * inv) << 16);
    u0.w = f2bf(o[1].z * inv) | (f2bf(o[1].w * inv) << 16);
    u1.x = f2bf(o[2].x * inv) | (f2bf(o[2].y * inv) << 16);
    u1.y = f2bf(o[2].z * inv) | (f2bf(o[2].w * inv) << 16);
    u1.z = f2bf(o[3].x * inv) | (f2bf(o[3].y * inv) << 16);
    u1.w = f2bf(o[3].z * inv) | (f2bf(o[3].w * inv) << 16);
    oAf[((size_t)tt * 64 + kb0) * 16 + m] = u0;
    oAf[((size_t)tt * 64 + kb0 + 1) * 16 + m] = u1;
}

extern "C" void kernel_launch(void* const* d_in, const int* in_sizes, int n_in,
                              void* d_out, int out_size, void* d_ws, size_t ws_size,
                              hipStream_t stream) {
    const void* model_embed = d_in[0];
    const void* ctx_key     = d_in[1];
    const void* ctx_val     = d_in[2];
    const void* ln1w = d_in[3];  const void* ln1b = d_in[4];
    const void* ln2w = d_in[5];  const void* ln2b = d_in[6];
    const void* ln3w = d_in[7];  const void* ln3b = d_in[8];
    const void* ln4w = d_in[9];  const void* ln4b = d_in[10];
    const void* wq = d_in[11];   const void* bq = d_in[12];
    const void* wk = d_in[13];   const void* bk = d_in[14];
    const void* wv = d_in[15];   const void* bv = d_in[16];
    const void* wo = d_in[17];   const void* bo = d_in[18];
    const void* wp = d_in[19];   const void* bp = d_in[20];

    int*   flagp = (int*)d_ws;
    float* ws    = (float*)d_ws + 16;
    float* o1    = ws;                         // 524288 fp32
    float* qTf   = o1 + 524288;                // qf   262144 fl (1 MB)
    float* kTf   = qTf + 262144;               // kf  2097152 fl (8 MB)
    float* Aqf   = kTf + 2097152;              // Aq   262144 fl
    float* Akf   = Aqf + 262144;               // Ak  2097152 fl
    float* Avf   = Akf + 2097152;              // Av   524288 fl
    float* vff   = Avf + 524288;               // vf   524288 fl (also oAf)
    float* pacc2 = vff + 524288;               // 4194304 fl (16 MB)
    float* pm2   = pacc2 + 4194304;            // 65536
    float* pl2   = pm2 + 65536;                // 65536
    float* wfr   = pl2 + 65536;                // 655360 fl (5 W-frags)

    uint4* qf  = (uint4*)qTf;
    uint4* kf  = (uint4*)kTf;
    uint4* Aq  = (uint4*)Aqf;
    uint4* Ak  = (uint4*)Akf;
    uint4* Av  = (uint4*)Avf;
    uint4* vf  = (uint4*)vff;
    uint4* oAf = (uint4*)vff;                  // reuse after attn consumes vf
    uint4* wfq = (uint4*)wfr;
    uint4* wfk = wfq + 32768;
    uint4* wfv = wfk + 32768;
    uint4* wfo = wfv + 32768;
    uint4* wfp = wfo + 32768;

    pack_all_kernel<<<1024, 256, 0, stream>>>(model_embed, ln1w, ln1b,
                                              ctx_key, ln2w, ln2b,
                                              ctx_val, ln3w, ln3b,
                                              Aq, Ak, Av,
                                              wq, wk, wv, wo, wp,
                                              wfq, wfk, wfv, wfo, wfp, flagp);

    gemm_qkv_kernel<<<1408, 256, 0, stream>>>(Aq, Ak, Av, wfq, wfk, wfv,
                                              bq, bk, bv, qf, kf, vf, flagp);

    attn_fused_kernel<<<1024, 256, 0, stream>>>(qf, kf, vf, pacc2, pm2, pl2);
    attn_merge2_kernel<<<128, 256, 0, stream>>>(pacc2, pm2, pl2, oAf);

    mfma_gemm_kernel<0><<<dim3(8, 16), 256, 0, stream>>>(oAf, wfo, bo, o1, nullptr, 0, flagp);
    pack_a_kernel<true><<<64, 256, 0, stream>>>(o1, 0, ln4w, ln4b, Aq, flagp);
    mfma_gemm_kernel<0><<<dim3(8, 16), 256, 0, stream>>>(Aq, wfp, bp, (float*)d_out, nullptr, 0, flagp);

    (void)ws_size;
}